// Round 1
// baseline (544.028 us; speedup 1.0000x reference)
//
#include <hip/hip_runtime.h>
#include <math.h>

// Problem constants (from the reference)
#define BB 8
#define TT 512
#define SS 512
#define HH 768
#define VOCAB 32110
#define HALF0 16056              // even split: both half-row bases stay 8B-aligned
#define LDSF  16056              // LDS floats per block (max(16056, 16054)) = 64224 B

// ---------------------------------------------------------------------------
// Kernel 1: p_gen = sigmoid(concat(dec,seq) @ w + b)   -> out[0 .. B*T)
// One wave (64 lanes) per (b,t) row; 1536-wide dot, shuffle reduce.
// ---------------------------------------------------------------------------
__global__ __launch_bounds__(256) void pgen_kernel(
    const float* __restrict__ dec,   // [B*T, H]
    const float* __restrict__ seq,   // [B*T, H]
    const float* __restrict__ w,     // [2H]
    const float* __restrict__ bptr,  // [1]
    float* __restrict__ out)         // [B*T]
{
    const int gid  = blockIdx.x * 256 + threadIdx.x;
    const int row  = gid >> 6;
    const int lane = threadIdx.x & 63;
    if (row >= BB * TT) return;

    const float* d = dec + (size_t)row * HH;
    const float* s = seq + (size_t)row * HH;

    float acc = 0.f;
    #pragma unroll
    for (int j0 = 0; j0 < HH; j0 += 64) {
        int j = j0 + lane;
        acc += d[j] * w[j] + s[j] * w[HH + j];
    }
    // wave64 butterfly reduce
    #pragma unroll
    for (int off = 32; off > 0; off >>= 1)
        acc += __shfl_down(acc, off, 64);

    if (lane == 0) {
        float x = acc + bptr[0];
        out[row] = 1.f / (1.f + expf(-x));
    }
}

// ---------------------------------------------------------------------------
// Kernel 2: logits[row, v] = sum_{s: ids[b,s]==v} attn[row, s]
// One block per (row, vocab-half). Compose the half-row in LDS (zero +
// LDS-atomic scatter of the 512 attn values), then stream out coalesced.
// 64224 B LDS/block -> 2 blocks/CU, 16 waves/CU.
// ---------------------------------------------------------------------------
__global__ __launch_bounds__(512, 4) void scatter_logits(
    const float* __restrict__ attn,  // [B*T, S]
    const int*   __restrict__ ids,   // [B, S]
    float* __restrict__ out_logits)  // [B*T, VOCAB]
{
    __shared__ float smem[LDSF];

    const int bid  = blockIdx.x;
    const int row  = bid >> 1;            // b*T + t
    const int half = bid & 1;
    const int lo   = half ? HALF0 : 0;
    const int n    = half ? (VOCAB - HALF0) : HALF0;   // 16054 or 16056, both even
    const int b    = row >> 9;            // row / T, T = 512
    const int tid  = threadIdx.x;

    // ---- zero LDS (b64 writes) ----
    float2* sm2 = reinterpret_cast<float2*>(smem);
    #pragma unroll 4
    for (int i = tid; i < LDSF / 2; i += 512) sm2[i] = make_float2(0.f, 0.f);
    __syncthreads();

    // ---- scatter: 512 (id, attn) pairs, LDS atomic add ----
    {
        const float* arow = attn + (size_t)row * SS;
        const int*   irow = ids  + (size_t)b * SS;
        int   v = irow[tid];          // blockDim.x == S == 512
        float a = arow[tid];
        int loc = v - lo;
        if ((unsigned)loc < (unsigned)n) atomicAdd(&smem[loc], a);
    }
    __syncthreads();

    // ---- stream the half-row out, coalesced float2 stores ----
    float* dst = out_logits + (size_t)row * VOCAB + lo;    // 8B-aligned (even float off)
    const float2* src2 = reinterpret_cast<const float2*>(smem);
    float2*       dst2 = reinterpret_cast<float2*>(dst);
    const int n2 = n >> 1;
    for (int i = tid; i < n2; i += 512) dst2[i] = src2[i];
}

// ---------------------------------------------------------------------------
extern "C" void kernel_launch(void* const* d_in, const int* in_sizes, int n_in,
                              void* d_out, int out_size, void* d_ws, size_t ws_size,
                              hipStream_t stream) {
    const float* dec  = (const float*)d_in[0];   // [B,T,H] f32
    const float* seq  = (const float*)d_in[1];   // [B,T,H] f32
    const float* attn = (const float*)d_in[2];   // [B,T,S] f32
    const int*   ids  = (const int*)  d_in[3];   // [B,S] int32
    const float* w    = (const float*)d_in[4];   // [2H,1] f32
    const float* bp   = (const float*)d_in[5];   // [1] f32

    float* out = (float*)d_out;                  // [B*T] p_gen ++ [B*T,VOCAB] logits

    // p_gen: 4096 rows, 1 wave each, 4 waves/block
    pgen_kernel<<<(BB * TT) / 4, 256, 0, stream>>>(dec, seq, w, bp, out);

    // logits: one block per (row, half)
    scatter_logits<<<BB * TT * 2, 512, 0, stream>>>(attn, ids, out + BB * TT);
}